// Round 9
// baseline (36.769 us; speedup 1.0000x reference)
//
#include <hip/hip_runtime.h>
#include <math.h>

#define NCOL 8192
#define BT   512
#define EPT  16
#define ROWS 8
#define NF4  2048   // float4 per row

// exact double constants
#define MZM_LOSS_D 0.8912509381337456   // 10^-0.05
#define YB_LOSS_D  0.9332543007969910   // 10^-0.03
#define MRR_LOSS_D 0.8912509381337456   // 10^-0.05

typedef __attribute__((address_space(3))) void       lds_void_t;
typedef const __attribute__((address_space(1))) void g_void_t;

static __device__ __forceinline__ void lds_barrier() {
    // drain LDS/SMEM only; global_load_lds prefetch stays in flight
    asm volatile("s_waitcnt lgkmcnt(0)" ::: "memory");
    __builtin_amdgcn_s_barrier();
}

// float4-level XOR swizzle (involution): spreads 64B-window reads across banks
static __device__ __forceinline__ int swz(int g) { return g ^ ((g >> 3) & 7); }

// Markstein: dst = rint(f32div(a, inorm) * 255), exact IEEE f32 division
#define QF(dst, a_) do {                                   \
    const float a__  = (a_);                               \
    const float q0__ = a__ * y;                            \
    const float r__  = fmaf(-inorm, q0__, a__);            \
    (dst) = rintf(fmaf(r__, y, q0__) * 255.f);             \
} while (0)

__global__ __launch_bounds__(BT, 4)
void odp_main(const float* __restrict__ x, const float* __restrict__ w,
              const float* __restrict__ ntp, const float* __restrict__ nsp,
              const float* __restrict__ ntn, const float* __restrict__ nsn,
              float* __restrict__ out)
{
    __shared__ float4 xs[2][NF4];     // 64 KB double buffer
    __shared__ float  redX[8], redW[8], redT[8];
    __shared__ double redD[8];
    __shared__ double corrd[4];       // cD(t0), cT(t0), cD(tLast), cT(tLast)

    const int t    = threadIdx.x;
    const int lane = t & 63;
    const int wid  = t >> 6;
    const int r0   = blockIdx.x * ROWS;

    const double DE0 = -((double)0.01f + (double)0.0025f);  // elems 0, N-1
    const double DE1 = -((double)0.0025f);                  // elems 1, N-2
    const double E_MID = 1.0 + 2.0 * (double)0.01f + 2.0 * (double)0.0025f;

    // ---- prologue: w -> regs (+ wave max|w|), stage row 0 into buf 0 ----
    const float4* __restrict__ w4 = (const float4*)w;
    float wf[EPT];
    float mw = 0.f;
#pragma unroll
    for (int j = 0; j < 4; ++j) {
        const float4 wv = w4[t * 4 + j];
        wf[4*j+0]=wv.x; wf[4*j+1]=wv.y; wf[4*j+2]=wv.z; wf[4*j+3]=wv.w;
        mw = fmaxf(mw, fmaxf(fmaxf(fabsf(wv.x), fabsf(wv.y)),
                             fmaxf(fabsf(wv.z), fabsf(wv.w))));
    }

#define STAGE(BUF, ROW) do {                                                  \
    const float* xr_ = x + (size_t)(ROW) * NCOL;                              \
    _Pragma("unroll")                                                         \
    for (int k = 0; k < 4; ++k) {                                             \
        const int phys_ = ((wid * 4 + k) << 6) | lane;                        \
        __builtin_amdgcn_global_load_lds(                                     \
            (g_void_t*)(xr_ + 4 * swz(phys_)),                                \
            (lds_void_t*)&xs[BUF][(wid * 4 + k) << 6], 16, 0, 0);             \
    }                                                                         \
} while (0)

    STAGE(0, r0);

    // precomputed swizzled read indices (same for both buffers)
    int wi[4];
#pragma unroll
    for (int k = 0; k < 4; ++k) wi[k] = swz(4 * t + k);
    const int hiL = swz((t > 0)      ? (4 * t - 1) : 0);        // dwords 16t-2,-1 in .z,.w
    const int hiR = swz((t < BT - 1) ? (4 * t + 4) : (NF4 - 1));// dwords 16t+16,+17 in .x,.y

    float wnorm = 1.f;     // valid in thread 0 after row 0
    float ov[ROWS];        // per-row outputs, thread 0 only

#pragma unroll
    for (int r = 0; r < ROWS; ++r) {
        const int buf = r & 1;
        if (r < ROWS - 1) {
            STAGE(buf ^ 1, r0 + r + 1);
            asm volatile("s_waitcnt vmcnt(4)" ::: "memory");  // row r staged; r+1 in flight
        } else {
            asm volatile("s_waitcnt vmcnt(0)" ::: "memory");
        }

        // ---- own 16 elems from LDS (conflict-free swizzled b128) ----
        float xf[EPT];
#pragma unroll
        for (int k = 0; k < 4; ++k) {
            const float4 v = xs[buf][wi[k]];
            xf[4*k+0]=v.x; xf[4*k+1]=v.y; xf[4*k+2]=v.z; xf[4*k+3]=v.w;
        }
        float mx = 0.f;
#pragma unroll
        for (int c = 0; c < EPT; ++c) mx = fmaxf(mx, fabsf(xf[c]));
#pragma unroll
        for (int off = 32; off; off >>= 1)
            mx = fmaxf(mx, __shfl_down(mx, off));
        if (lane == 0) redX[wid] = mx;
        lds_barrier();   // #1 — all waves' stages of row r complete + redX visible

        float inorm = redX[0];
#pragma unroll
        for (int i = 1; i < 8; ++i) inorm = fmaxf(inorm, redX[i]);
        inorm = (inorm <= 1e-9f) ? 1.f : inorm;
        const double inv_d = 1.0 / (double)inorm;   // correctly-rounded f32 recip seed
        const float  y     = (float)inv_d;

        // halos (cross-wave staged data — safe after barrier #1)
        const float4 hv1 = xs[buf][hiL];
        const float4 hv2 = xs[buf][hiR];

        float Q[EPT + 4];
#pragma unroll
        for (int c = 0; c < EPT; ++c) QF(Q[c + 2], fabsf(xf[c]));
        QF(Q[0],  fabsf(hv1.z)); QF(Q[1],  fabsf(hv1.w));
        QF(Q[18], fabsf(hv2.x)); QF(Q[19], fabsf(hv2.y));
        if (t == 0)      { Q[0]  = 0.f; Q[1]  = 0.f; }   // conv 'SAME' zero pad
        if (t == BT - 1) { Q[18] = 0.f; Q[19] = 0.f; }

        // ---- conv + D/T accumulate (4 rotating f32 chains, R4-identical) ----
        float Dv[4] = {0.f,0.f,0.f,0.f}, Tv[4] = {0.f,0.f,0.f,0.f};
        double cD = 0.0, cT = 0.0;
#pragma unroll
        for (int c = 0; c < EPT; ++c) {
            const float s1 = Q[c + 1] + Q[c + 3];
            const float s2 = Q[c]     + Q[c + 4];
            float cv = fmaf(0.01f, s1, Q[c + 2]);
            cv = fmaf(0.0025f, s2, cv);
            const float sel = (xf[c] > 0.f) ? wf[c] : -wf[c];
            Dv[c & 3] = fmaf(cv, sel,        Dv[c & 3]);
            Tv[c & 3] = fmaf(cv, fabsf(sel), Tv[c & 3]);
        }
        if (t == 0) {
#pragma unroll
            for (int c = 0; c < 2; ++c) {
                const float s1 = Q[c + 1] + Q[c + 3];
                const float s2 = Q[c]     + Q[c + 4];
                float cv = fmaf(0.01f, s1, Q[c + 2]);
                cv = fmaf(0.0025f, s2, cv);
                const float sel = (xf[c] > 0.f) ? wf[c] : -wf[c];
                const double de = (c == 0) ? DE0 : DE1;
                cD += de * (double)(cv * sel);
                cT += de * (double)(cv * fabsf(sel));
            }
        }
        if (t == BT - 1) {
#pragma unroll
            for (int c = EPT - 2; c < EPT; ++c) {
                const float s1 = Q[c + 1] + Q[c + 3];
                const float s2 = Q[c]     + Q[c + 4];
                float cv = fmaf(0.01f, s1, Q[c + 2]);
                cv = fmaf(0.0025f, s2, cv);
                const float sel = (xf[c] > 0.f) ? wf[c] : -wf[c];
                const double de = (c == EPT - 1) ? DE0 : DE1;
                cD += de * (double)(cv * sel);
                cT += de * (double)(cv * fabsf(sel));
            }
        }

        double accD = ((double)Dv[0] + (double)Dv[1]) + ((double)Dv[2] + (double)Dv[3]);
        float  accT = (Tv[0] + Tv[1]) + (Tv[2] + Tv[3]);
        float  mww  = mw;
#pragma unroll
        for (int off = 32; off; off >>= 1) {
            accD += __shfl_down(accD, off);
            accT += __shfl_down(accT, off);
            mww   = fmaxf(mww, __shfl_down(mww, off));
        }
        if (lane == 0)   { redD[wid] = accD; redT[wid] = accT; redW[wid] = mww; }
        if (t == 0)      { corrd[0] = cD; corrd[1] = cT; }
        if (t == BT - 1) { corrd[2] = cD; corrd[3] = cT; }
        lds_barrier();   // #2

        if (t == 0) {
            double D = 0.0, T = 0.0;
            float wn = redW[0];
#pragma unroll
            for (int i = 0; i < 8; ++i) {
                D += redD[i]; T += (double)redT[i];
                wn = fmaxf(wn, redW[i]);
            }
            if (r == 0) wnorm = (wn <= 1e-9f) ? 1.f : wn;

            D = D * E_MID + (corrd[0] + corrd[2]);
            T = T * E_MID + (corrd[1] + corrd[3]);

            const double Kd = (10.0 / 255.0) * (YB_LOSS_D * MZM_LOSS_D) / (double)wnorm;
            const double ps = (T + D) * 0.5 * Kd * MRR_LOSS_D;
            const double ns = (T - D) * 0.5 * Kd * MRR_LOSS_D;

            const float thermal_f = 3.3135576e-12f;   // f32(4*kB*T*Hz/R)
            const float shot_f    = 3.204353268e-9f;  // f32(2*qE*Hz)
            const int   row_      = r0 + r;

            double tp_ = ps + 1e-12 + (double)(ntp[row_] * thermal_f);
            tp_ *= (double)(1.0f + nsp[row_] * shot_f);   // == *1.0 in f32, faithful
            double tn_ = ns + 1e-12 + (double)(ntn[row_] * thermal_f);
            tn_ *= (double)(1.0f + nsn[row_] * shot_f);

            const double cur = tp_ - tn_;
            double v = fabs(cur * 100.0);
            v = fmin(v, 1.0);
            const double va  = rint(v * 255.0) * (1.0 / 255.0);
            const double sgn = (cur >= 0.0) ? 1.0 : -1.0;
            const double scale = (double)wnorm /
                (10.0 * 100.0 * MRR_LOSS_D * YB_LOSS_D * MZM_LOSS_D);
            ov[r] = (float)(va * sgn * scale * (double)inorm);
        }
    }

    // ---- epilogue: thread 0 writes the block's 8 outputs ----
    if (t == 0) {
        float4 o0 = make_float4(ov[0], ov[1], ov[2], ov[3]);
        float4 o1 = make_float4(ov[4], ov[5], ov[6], ov[7]);
        *(float4*)(out + r0)     = o0;
        *(float4*)(out + r0 + 4) = o1;
    }
#undef STAGE
}

extern "C" void kernel_launch(void* const* d_in, const int* in_sizes, int n_in,
                              void* d_out, int out_size, void* d_ws, size_t ws_size,
                              hipStream_t stream) {
    const float* x   = (const float*)d_in[0];
    const float* w   = (const float*)d_in[1];
    const float* ntp = (const float*)d_in[2];
    const float* nsp = (const float*)d_in[3];
    const float* ntn = (const float*)d_in[4];
    const float* nsn = (const float*)d_in[5];
    float* out = (float*)d_out;
    const int nblocks = out_size / ROWS;   // B=4096 -> 512 blocks, 2/CU, persistent
    odp_main<<<dim3(nblocks), dim3(BT), 0, stream>>>(x, w, ntp, nsp, ntn, nsn, out);
}

// Round 10
// 36.466 us; speedup vs baseline: 1.0083x; 1.0083x over previous
//
#include <hip/hip_runtime.h>
#include <math.h>

#define NCOL 8192
#define BT   512
#define EPT  16
#define ROWS 8
#define NF4  2048   // float4 per row

// exact double constants
#define MZM_LOSS_D 0.8912509381337456   // 10^-0.05
#define YB_LOSS_D  0.9332543007969910   // 10^-0.03
#define MRR_LOSS_D 0.8912509381337456   // 10^-0.05

typedef __attribute__((address_space(3))) void       lds_void_t;
typedef const __attribute__((address_space(1))) void g_void_t;

static __device__ __forceinline__ void lds_barrier() {
    // drain LDS/SMEM only; global_load_lds prefetch stays in flight
    asm volatile("s_waitcnt lgkmcnt(0)" ::: "memory");
    __builtin_amdgcn_s_barrier();
}

// float4-level XOR swizzle (involution): spreads 64B-window reads across banks
static __device__ __forceinline__ int swz(int g) { return g ^ ((g >> 3) & 7); }

// Markstein: dst = rint(f32div(a, inorm) * 255), exact IEEE f32 division
#define QF(dst, a_) do {                                   \
    const float a__  = (a_);                               \
    const float q0__ = a__ * y;                            \
    const float r__  = fmaf(-inorm, q0__, a__);            \
    (dst) = rintf(fmaf(r__, y, q0__) * 255.f);             \
} while (0)

__global__ __launch_bounds__(BT, 4)
void odp_main(const float* __restrict__ x, const float* __restrict__ w,
              const float* __restrict__ ntp, const float* __restrict__ nsp,
              const float* __restrict__ ntn, const float* __restrict__ nsn,
              float* __restrict__ out)
{
    __shared__ float4 xs[2][NF4];     // 64 KB double buffer
    __shared__ float  redX[8], redW[8], redT[8];
    __shared__ double redD[8];
    __shared__ double corrd[4];       // cD(t0), cT(t0), cD(tLast), cT(tLast)

    const int t    = threadIdx.x;
    const int lane = t & 63;
    const int wid  = t >> 6;
    const int r0   = blockIdx.x * ROWS;

    const double DE0 = -((double)0.01f + (double)0.0025f);  // elems 0, N-1
    const double DE1 = -((double)0.0025f);                  // elems 1, N-2
    const double E_MID = 1.0 + 2.0 * (double)0.01f + 2.0 * (double)0.0025f;

    // ---- prologue: w -> regs (+ wave max|w|), stage row 0 into buf 0 ----
    const float4* __restrict__ w4 = (const float4*)w;
    float wf[EPT];
    float mw = 0.f;
#pragma unroll
    for (int j = 0; j < 4; ++j) {
        const float4 wv = w4[t * 4 + j];
        wf[4*j+0]=wv.x; wf[4*j+1]=wv.y; wf[4*j+2]=wv.z; wf[4*j+3]=wv.w;
        mw = fmaxf(mw, fmaxf(fmaxf(fabsf(wv.x), fabsf(wv.y)),
                             fmaxf(fabsf(wv.z), fabsf(wv.w))));
    }

#define STAGE(BUF, ROW) do {                                                  \
    const float* xr_ = x + (size_t)(ROW) * NCOL;                              \
    _Pragma("unroll")                                                         \
    for (int k = 0; k < 4; ++k) {                                             \
        const int phys_ = ((wid * 4 + k) << 6) | lane;                        \
        __builtin_amdgcn_global_load_lds(                                     \
            (g_void_t*)(xr_ + 4 * swz(phys_)),                                \
            (lds_void_t*)&xs[BUF][(wid * 4 + k) << 6], 16, 0, 0);             \
    }                                                                         \
} while (0)

    STAGE(0, r0);

    // precomputed swizzled read indices (same for both buffers)
    int wi[4];
#pragma unroll
    for (int k = 0; k < 4; ++k) wi[k] = swz(4 * t + k);
    const int hiL = swz((t > 0)      ? (4 * t - 1) : 0);        // dwords 16t-2,-1 in .z,.w
    const int hiR = swz((t < BT - 1) ? (4 * t + 4) : (NF4 - 1));// dwords 16t+16,+17 in .x,.y

    float wnorm = 1.f;     // valid in thread 0 after row 0
    float ov[ROWS];        // per-row outputs, thread 0 only

#pragma unroll
    for (int r = 0; r < ROWS; ++r) {
        const int buf = r & 1;
        if (r < ROWS - 1) {
            STAGE(buf ^ 1, r0 + r + 1);
            asm volatile("s_waitcnt vmcnt(4)" ::: "memory");  // row r staged; r+1 in flight
        } else {
            asm volatile("s_waitcnt vmcnt(0)" ::: "memory");
        }

        // ---- own 16 elems from LDS (conflict-free swizzled b128) ----
        float xf[EPT];
#pragma unroll
        for (int k = 0; k < 4; ++k) {
            const float4 v = xs[buf][wi[k]];
            xf[4*k+0]=v.x; xf[4*k+1]=v.y; xf[4*k+2]=v.z; xf[4*k+3]=v.w;
        }
        float mx = 0.f;
#pragma unroll
        for (int c = 0; c < EPT; ++c) mx = fmaxf(mx, fabsf(xf[c]));
#pragma unroll
        for (int off = 32; off; off >>= 1)
            mx = fmaxf(mx, __shfl_down(mx, off));
        if (lane == 0) redX[wid] = mx;
        lds_barrier();   // #1 — all waves' stages of row r complete + redX visible

        float inorm = redX[0];
#pragma unroll
        for (int i = 1; i < 8; ++i) inorm = fmaxf(inorm, redX[i]);
        inorm = (inorm <= 1e-9f) ? 1.f : inorm;
        const double inv_d = 1.0 / (double)inorm;   // correctly-rounded f32 recip seed
        const float  y     = (float)inv_d;

        // halos (cross-wave staged data — safe after barrier #1)
        const float4 hv1 = xs[buf][hiL];
        const float4 hv2 = xs[buf][hiR];

        float Q[EPT + 4];
#pragma unroll
        for (int c = 0; c < EPT; ++c) QF(Q[c + 2], fabsf(xf[c]));
        QF(Q[0],  fabsf(hv1.z)); QF(Q[1],  fabsf(hv1.w));
        QF(Q[18], fabsf(hv2.x)); QF(Q[19], fabsf(hv2.y));
        if (t == 0)      { Q[0]  = 0.f; Q[1]  = 0.f; }   // conv 'SAME' zero pad
        if (t == BT - 1) { Q[18] = 0.f; Q[19] = 0.f; }

        // ---- conv + D/T accumulate (4 rotating f32 chains, R4-identical) ----
        float Dv[4] = {0.f,0.f,0.f,0.f}, Tv[4] = {0.f,0.f,0.f,0.f};
        double cD = 0.0, cT = 0.0;
#pragma unroll
        for (int c = 0; c < EPT; ++c) {
            const float s1 = Q[c + 1] + Q[c + 3];
            const float s2 = Q[c]     + Q[c + 4];
            float cv = fmaf(0.01f, s1, Q[c + 2]);
            cv = fmaf(0.0025f, s2, cv);
            const float sel = (xf[c] > 0.f) ? wf[c] : -wf[c];
            Dv[c & 3] = fmaf(cv, sel,        Dv[c & 3]);
            Tv[c & 3] = fmaf(cv, fabsf(sel), Tv[c & 3]);
        }
        if (t == 0) {
#pragma unroll
            for (int c = 0; c < 2; ++c) {
                const float s1 = Q[c + 1] + Q[c + 3];
                const float s2 = Q[c]     + Q[c + 4];
                float cv = fmaf(0.01f, s1, Q[c + 2]);
                cv = fmaf(0.0025f, s2, cv);
                const float sel = (xf[c] > 0.f) ? wf[c] : -wf[c];
                const double de = (c == 0) ? DE0 : DE1;
                cD += de * (double)(cv * sel);
                cT += de * (double)(cv * fabsf(sel));
            }
        }
        if (t == BT - 1) {
#pragma unroll
            for (int c = EPT - 2; c < EPT; ++c) {
                const float s1 = Q[c + 1] + Q[c + 3];
                const float s2 = Q[c]     + Q[c + 4];
                float cv = fmaf(0.01f, s1, Q[c + 2]);
                cv = fmaf(0.0025f, s2, cv);
                const float sel = (xf[c] > 0.f) ? wf[c] : -wf[c];
                const double de = (c == EPT - 1) ? DE0 : DE1;
                cD += de * (double)(cv * sel);
                cT += de * (double)(cv * fabsf(sel));
            }
        }

        double accD = ((double)Dv[0] + (double)Dv[1]) + ((double)Dv[2] + (double)Dv[3]);
        float  accT = (Tv[0] + Tv[1]) + (Tv[2] + Tv[3]);
        float  mww  = mw;
#pragma unroll
        for (int off = 32; off; off >>= 1) {
            accD += __shfl_down(accD, off);
            accT += __shfl_down(accT, off);
            mww   = fmaxf(mww, __shfl_down(mww, off));
        }
        if (lane == 0)   { redD[wid] = accD; redT[wid] = accT; redW[wid] = mww; }
        if (t == 0)      { corrd[0] = cD; corrd[1] = cT; }
        if (t == BT - 1) { corrd[2] = cD; corrd[3] = cT; }
        lds_barrier();   // #2

        if (t == 0) {
            double D = 0.0, T = 0.0;
            float wn = redW[0];
#pragma unroll
            for (int i = 0; i < 8; ++i) {
                D += redD[i]; T += (double)redT[i];
                wn = fmaxf(wn, redW[i]);
            }
            if (r == 0) wnorm = (wn <= 1e-9f) ? 1.f : wn;

            D = D * E_MID + (corrd[0] + corrd[2]);
            T = T * E_MID + (corrd[1] + corrd[3]);

            const double Kd = (10.0 / 255.0) * (YB_LOSS_D * MZM_LOSS_D) / (double)wnorm;
            const double ps = (T + D) * 0.5 * Kd * MRR_LOSS_D;
            const double ns = (T - D) * 0.5 * Kd * MRR_LOSS_D;

            const float thermal_f = 3.3135576e-12f;   // f32(4*kB*T*Hz/R)
            const float shot_f    = 3.204353268e-9f;  // f32(2*qE*Hz)
            const int   row_      = r0 + r;

            double tp_ = ps + 1e-12 + (double)(ntp[row_] * thermal_f);
            tp_ *= (double)(1.0f + nsp[row_] * shot_f);   // == *1.0 in f32, faithful
            double tn_ = ns + 1e-12 + (double)(ntn[row_] * thermal_f);
            tn_ *= (double)(1.0f + nsn[row_] * shot_f);

            const double cur = tp_ - tn_;
            double v = fabs(cur * 100.0);
            v = fmin(v, 1.0);
            const double va  = rint(v * 255.0) * (1.0 / 255.0);
            const double sgn = (cur >= 0.0) ? 1.0 : -1.0;
            const double scale = (double)wnorm /
                (10.0 * 100.0 * MRR_LOSS_D * YB_LOSS_D * MZM_LOSS_D);
            ov[r] = (float)(va * sgn * scale * (double)inorm);
        }
    }

    // ---- epilogue: thread 0 writes the block's 8 outputs ----
    if (t == 0) {
        float4 o0 = make_float4(ov[0], ov[1], ov[2], ov[3]);
        float4 o1 = make_float4(ov[4], ov[5], ov[6], ov[7]);
        *(float4*)(out + r0)     = o0;
        *(float4*)(out + r0 + 4) = o1;
    }
#undef STAGE
}

extern "C" void kernel_launch(void* const* d_in, const int* in_sizes, int n_in,
                              void* d_out, int out_size, void* d_ws, size_t ws_size,
                              hipStream_t stream) {
    const float* x   = (const float*)d_in[0];
    const float* w   = (const float*)d_in[1];
    const float* ntp = (const float*)d_in[2];
    const float* nsp = (const float*)d_in[3];
    const float* ntn = (const float*)d_in[4];
    const float* nsn = (const float*)d_in[5];
    float* out = (float*)d_out;
    const int nblocks = out_size / ROWS;   // B=4096 -> 512 blocks, 2/CU, persistent
    odp_main<<<dim3(nblocks), dim3(BT), 0, stream>>>(x, w, ntp, nsp, ntn, nsn, out);
}